// Round 5
// baseline (124.604 us; speedup 1.0000x reference)
//
#include <hip/hip_runtime.h>

typedef unsigned short u16;
typedef unsigned int u32;
typedef _Float16 half8 __attribute__((ext_vector_type(8)));   // MFMA A/B frag
typedef __attribute__((ext_vector_type(4))) float floatx4;    // MFMA acc

#define LSTRIDE 72            // u16 per LDS row (64 data + 8 pad); row = +4 banks
#define TILE (128 * LSTRIDE)  // u16 per tile (18432 B)

// ---------------------------------------------------------------------------
// Single dispatch, 4 blocks/CU (LDS 38.1KB, no spills: peak VGPR ~58 + 64 AGPR).
//   out[sub][p*8+q][o] = S*acc - K1*csum[o],  S = 2/255, K1 = 1024*S+1
//   acc = sum_m fp16(1024 + w[q][m]) * fp16(Wpad[m - p][o])
// BM=128 (16 subs x 8 q), BN=128 (2 p x 64 o), BK=64. 4 waves 2x2, 64x64.
// Schedule/iter: [issue x+W loads for kc+1] -> MFMA(kc) -> barrier ->
//   stage A/B(kc+1) (cvt/pack consume prefetched regs) -> barrier.
// LDS bank-conflict fix: 16B chunk index XOR-swizzled with (row>>3)&7 on both
// writes and reads (A-writes were 4-way, B-writes 8-way, reads 2-way before).
// Epilogue: LDS-staged two halves -> fully-coalesced 1KB/wave-instr stores.
// ---------------------------------------------------------------------------
__global__ __launch_bounds__(256, 4) void byteformer_fused(
    const int* __restrict__ x, const float* __restrict__ Wm,
    float* __restrict__ out) {
  __shared__ __align__(16) u16 arena[2 * TILE];   // As | Bs = 36864 B
  __shared__ float part[256];
  __shared__ float csumsh[64];
  u16* As = arena;
  u16* Bs = arena + TILE;

  const int t = threadIdx.x;
  const int mtile = blockIdx.x;        // 0..127 (16 sub-blocks each)
  const int y = blockIdx.y;            // 0..7: p in {2y, 2y+1}

  const int wave = t >> 6, lane = t & 63;
  const int wm = wave >> 1, wn = wave & 1;
  const int quad = lane >> 4, l16 = lane & 15;

  // A staging: thread -> (sub, k-group, q-half)
  const int sA_sub = t >> 4;           // 0..15  (= wave*4 + quad)
  const int sA_kg  = (t >> 1) & 7;     // 0..7
  const int sA_qh  = t & 1;            // 0..1
  const long xrow = ((long)mtile * 16 + sA_sub) * 512;

  floatx4 acc[4][4];
  #pragma unroll
  for (int mt = 0; mt < 4; ++mt)
    #pragma unroll
    for (int nt = 0; nt < 4; ++nt)
      acc[mt][nt] = floatx4{0.f, 0.f, 0.f, 0.f};

  float csum_local = 0.0f;

  // ---- register prefetch state (live across compute: 9 + 17 VGPRs)
  int4 ca, cb; int cc;                 // x bytes (9 ints)
  float fv[17];                        // W rows (fp32, cvt'd at stage time)

  auto xload = [&](int kc) {
    const int base = kc * 64 + sA_kg * 8;
    ca = *(const int4*)&x[xrow + base];
    cb = *(const int4*)&x[xrow + base + 4];
    cc = (base + 8 < 512) ? x[xrow + base + 8] : 0;
  };

  auto wload = [&](int kc) {           // wave-uniform col, lane = o: coalesced
    const int cbase = kc * 64 + 16 * wave - 2 * y - 1;
    #pragma unroll
    for (int j = 0; j < 17; ++j) {
      const int c = cbase + j;
      fv[j] = (c >= 0 && c < 496) ? Wm[c * 64 + lane] : 0.0f;
    }
  };

  // bytes -> windows -> fp16(1024+v) via 0x6400|v; P-trick; swizzled b128 write
  auto astage = [&]() {
    const u32 c0 = (u32)ca.x, c1 = (u32)ca.y, c2 = (u32)ca.z, c3 = (u32)ca.w;
    const u32 c4 = (u32)cb.x, c5 = (u32)cb.y, c6 = (u32)cb.z, c7 = (u32)cb.w;
    const u32 c8 = (u32)cc;
    const u32 P0 = ((c0 << 8) | c1) | (((c1 << 8) | c2) << 16);
    const u32 P1 = ((c2 << 8) | c3) | (((c3 << 8) | c4) << 16);
    const u32 P2 = ((c4 << 8) | c5) | (((c5 << 8) | c6) << 16);
    const u32 P3 = ((c6 << 8) | c7) | (((c7 << 8) | c8) << 16);
    // rows sA_sub*8 + sA_qh*4 + qi; (row>>3)&7 == sA_sub&7 for all qi
    u16* arow = &As[(sA_sub * 8 + sA_qh * 4) * LSTRIDE +
                    ((sA_kg ^ (sA_sub & 7)) << 3)];
    #pragma unroll
    for (int qi = 0; qi < 4; ++qi) {
      const int sh = 8 - (sA_qh * 4 + qi);
      int4 d;
      d.x = (int)(((P0 >> sh) & 0x00FF00FFu) | 0x64006400u);
      d.y = (int)(((P1 >> sh) & 0x00FF00FFu) | 0x64006400u);
      d.z = (int)(((P2 >> sh) & 0x00FF00FFu) | 0x64006400u);
      d.w = (int)(((P3 >> sh) & 0x00FF00FFu) | 0x64006400u);
      *(int4*)(arow + qi * LSTRIDE) = d;   // rows 16B-aligned (144B pitch)
    }
  };

  // fv -> csum + fp16 pairs -> two m-groups x two p-shifts, swizzled b128 writes
  auto bstage = [&]() {
    #pragma unroll
    for (int j = 1; j <= 16; ++j) csum_local += fv[j];  // pp=0 coverage: full W
    u32 hp[9];                         // transient: not live across compute
    #pragma unroll
    for (int i = 0; i < 8; ++i) {
      u32 h0 = __builtin_bit_cast(unsigned short, (_Float16)fv[2 * i]);
      u32 h1 = __builtin_bit_cast(unsigned short, (_Float16)fv[2 * i + 1]);
      hp[i] = h0 | (h1 << 16);
    }
    hp[8] = (u32)__builtin_bit_cast(unsigned short, (_Float16)fv[16]);
    const int physc = lane >> 3;       // (row>>3)&7 == lane>>3 for both pp
    #pragma unroll
    for (int g = 0; g < 2; ++g) {
      const int mgrp = 2 * wave + g;
      const int ch = (mgrp ^ physc) << 3;
      int4 d1;                          // pp=1: even pairs, direct
      d1.x = (int)hp[4 * g + 0];
      d1.y = (int)hp[4 * g + 1];
      d1.z = (int)hp[4 * g + 2];
      d1.w = (int)hp[4 * g + 3];
      *(int4*)&Bs[(64 + lane) * LSTRIDE + ch] = d1;
      int4 d0;                          // pp=0: odd pairs, alignbit extract
      d0.x = (int)((hp[4 * g + 0] >> 16) | (hp[4 * g + 1] << 16));
      d0.y = (int)((hp[4 * g + 1] >> 16) | (hp[4 * g + 2] << 16));
      d0.z = (int)((hp[4 * g + 2] >> 16) | (hp[4 * g + 3] << 16));
      d0.w = (int)((hp[4 * g + 3] >> 16) | (hp[4 * g + 4] << 16));
      *(int4*)&Bs[lane * LSTRIDE + ch] = d0;
    }
  };

  auto compute_ks = [&](int ks) {
    half8 bf[4];
    #pragma unroll
    for (int nt = 0; nt < 4; ++nt) {
      const int row = wn * 64 + nt * 16 + l16;
      const int ch = ((ks * 4 + quad) ^ ((row >> 3) & 7)) << 3;
      bf[nt] = *(const half8*)&Bs[row * LSTRIDE + ch];
    }
    #pragma unroll
    for (int mt = 0; mt < 4; ++mt) {
      const int row = wm * 64 + mt * 16 + l16;
      const int ch = ((ks * 4 + quad) ^ ((row >> 3) & 7)) << 3;
      half8 af = *(const half8*)&As[row * LSTRIDE + ch];
      #pragma unroll
      for (int nt = 0; nt < 4; ++nt)
        acc[mt][nt] = __builtin_amdgcn_mfma_f32_16x16x32_f16(
            af, bf[nt], acc[mt][nt], 0, 0, 0);
    }
  };

  // ---- prologue: stage kc=0 (one-time exposed latency)
  xload(0); wload(0);
  astage(); bstage();
  __syncthreads();

  // ---- main loop: single-buffered, 2 barriers/iter; loads in MFMA shadow
  for (int kc = 0; kc < 8; ++kc) {
    if (kc < 7) { xload(kc + 1); wload(kc + 1); }  // latency under MFMA below
    compute_ks(0);
    compute_ks(1);
    if (kc < 7) {
      __syncthreads();                 // all reads of tile kc done
      astage();                        // consume prefetched regs (pure VALU)
      bstage();
      __syncthreads();                 // tile kc+1 published
    }
  }

  // ---- csum reduction -> K1 * colsum(W)
  const float S = 2.0f / 255.0f;
  const float K1 = 1024.0f * S + 1.0f;
  part[t] = csum_local;
  __syncthreads();                     // also: all tile reads done, arena free
  if (t < 64)
    csumsh[t] = K1 * (part[t] + part[t + 64] + part[t + 128] + part[t + 192]);
  __syncthreads();

  float cs[4];
  #pragma unroll
  for (int nt = 0; nt < 4; ++nt) cs[nt] = csumsh[nt * 16 + l16];

  // ---- epilogue: two halves (8 subs each) staged in LDS (pitch 1040 f32),
  // then fully-coalesced stores: 64 lanes x 16B = 1KB contiguous per instr.
  float* ep = (float*)arena;           // 33280 B per half <= 36864
  #pragma unroll
  for (int h = 0; h < 2; ++h) {
    if (wm == h) {                     // waves wm==h own subs h*8..h*8+7
      #pragma unroll
      for (int mt = 0; mt < 4; ++mt)
        #pragma unroll
        for (int i = 0; i < 4; ++i) {
          const int mr = mt * 16 + quad * 4 + i;   // 0..63 local
          const int rowbase = (mr >> 3) * 1040 + wn * 512 + (mr & 7) * 64 + l16;
          #pragma unroll
          for (int nt = 0; nt < 4; ++nt)
            ep[rowbase + nt * 16] = __builtin_fmaf(S, acc[mt][nt][i], -cs[nt]);
        }
    }
    __syncthreads();
    const long outb =
        ((long)mtile * 16 + (long)h * 8) * 8192 + (long)y * 1024;
    #pragma unroll
    for (int k2 = 0; k2 < 8; ++k2) {
      const float4 v =
          *(const float4*)((const char*)ep + k2 * 4160 + wave * 1024 + lane * 16);
      *(float4*)&out[outb + (long)k2 * 8192 + wave * 256 + lane * 4] = v;
    }
    if (h == 0) __syncthreads();       // half-0 LDS reads done before re-stage
  }
}

extern "C" void kernel_launch(void* const* d_in, const int* in_sizes, int n_in,
                              void* d_out, int out_size, void* d_ws, size_t ws_size,
                              hipStream_t stream) {
  const int* x = (const int*)d_in[0];        // (256, 4096) byte values as int32
  const float* Wm = (const float*)d_in[1];   // (496, 64) fp32
  float* out = (float*)d_out;                // (256, 8, 128, 64) fp32
  byteformer_fused<<<dim3(128, 8), dim3(256), 0, stream>>>(x, Wm, out);
}

// Round 6
// 105.870 us; speedup vs baseline: 1.1769x; 1.1769x over previous
//
#include <hip/hip_runtime.h>

typedef unsigned short u16;
typedef unsigned int u32;
typedef _Float16 half8 __attribute__((ext_vector_type(8)));   // MFMA A/B frag
typedef __attribute__((ext_vector_type(4))) float floatx4;    // MFMA acc

#define LSTRIDE 72            // u16 per LDS row (64 data + 8 pad); bank-clean
#define TILE (128 * LSTRIDE)  // u16 per tile (18432 B)

// ---------------------------------------------------------------------------
// Single dispatch, 4 blocks/CU (LDS 38.4KB; unified regs 64 VGPR + 64 AGPR).
//   out[sub][p*8+q][o] = S*acc - K1*csum[o],  S = 2/255, K1 = 1024*S+1
//   acc = sum_m fp16(1024 + w[q][m]) * fp16(Wpad[m - p][o])
// BM=128 (16 subs x 8 q), BN=128 (2 p x 64 o), BK=64. 4 waves 2x2, 64x64.
// Schedule/iter:
//   MFMA ks0  ->  [sched_barrier; issue x+W loads for kc+1]  ->  MFMA ks1
//   -> barrier -> stage A/B(kc+1): pack/cvt consume arrived loads -> barrier
// Load dest regs (26) are live only during ks1 -> no spill at 64 VGPR.
// sched_barrier(0x38F) = all-but-VMEM may cross: stops load hoisting above ks0.
// Bank "conflicts" (2.6M) are inherent b128 multi-phase cost - not addressed.
// Epilogue: LDS-staged two halves -> fully-coalesced 1KB/wave-instr stores.
// ---------------------------------------------------------------------------
__global__ __launch_bounds__(256, 4) void byteformer_fused(
    const int* __restrict__ x, const float* __restrict__ Wm,
    float* __restrict__ out) {
  __shared__ __align__(16) u16 arena[2 * TILE];   // As | Bs = 36864 B
  __shared__ float part[256];
  __shared__ float csumsh[64];
  u16* As = arena;
  u16* Bs = arena + TILE;

  const int t = threadIdx.x;
  const int mtile = blockIdx.x;        // 0..127 (16 sub-blocks each)
  const int y = blockIdx.y;            // 0..7: p in {2y, 2y+1}

  const int wave = t >> 6, lane = t & 63;
  const int wm = wave >> 1, wn = wave & 1;
  const int quad = lane >> 4, l16 = lane & 15;

  // A staging: thread -> (sub, k-group, q-half)
  const int sA_sub = t >> 4;           // 0..15
  const int sA_kg  = (t >> 1) & 7;     // 0..7
  const int sA_qh  = t & 1;            // 0..1
  const long xrow = ((long)mtile * 16 + sA_sub) * 512;

  floatx4 acc[4][4];
  #pragma unroll
  for (int mt = 0; mt < 4; ++mt)
    #pragma unroll
    for (int nt = 0; nt < 4; ++nt)
      acc[mt][nt] = floatx4{0.f, 0.f, 0.f, 0.f};

  float csum_local = 0.0f;

  // ---- register prefetch state (live only during ks1: 9 + 17 VGPRs)
  int4 ca, cb; int cc;                 // x bytes (9 ints)
  float fv[17];                        // W rows (fp32, cvt'd at stage time)

  auto xload = [&](int kc) {
    const int base = kc * 64 + sA_kg * 8;
    ca = *(const int4*)&x[xrow + base];
    cb = *(const int4*)&x[xrow + base + 4];
    cc = (base + 8 < 512) ? x[xrow + base + 8] : 0;
  };

  auto wload = [&](int kc) {           // wave-uniform col, lane = o: coalesced
    const int cbase = kc * 64 + 16 * wave - 2 * y - 1;
    #pragma unroll
    for (int j = 0; j < 17; ++j) {
      const int c = cbase + j;
      fv[j] = (c >= 0 && c < 496) ? Wm[c * 64 + lane] : 0.0f;
    }
  };

  // bytes -> windows -> fp16(1024+v) via 0x6400|v; P-trick; b128 writes
  auto astage = [&]() {
    const u32 c0 = (u32)ca.x, c1 = (u32)ca.y, c2 = (u32)ca.z, c3 = (u32)ca.w;
    const u32 c4 = (u32)cb.x, c5 = (u32)cb.y, c6 = (u32)cb.z, c7 = (u32)cb.w;
    const u32 c8 = (u32)cc;
    const u32 P0 = ((c0 << 8) | c1) | (((c1 << 8) | c2) << 16);
    const u32 P1 = ((c2 << 8) | c3) | (((c3 << 8) | c4) << 16);
    const u32 P2 = ((c4 << 8) | c5) | (((c5 << 8) | c6) << 16);
    const u32 P3 = ((c6 << 8) | c7) | (((c7 << 8) | c8) << 16);
    u16* arow = &As[(sA_sub * 8 + sA_qh * 4) * LSTRIDE + sA_kg * 8];
    #pragma unroll
    for (int qi = 0; qi < 4; ++qi) {
      const int sh = 8 - (sA_qh * 4 + qi);
      int4 d;
      d.x = (int)(((P0 >> sh) & 0x00FF00FFu) | 0x64006400u);
      d.y = (int)(((P1 >> sh) & 0x00FF00FFu) | 0x64006400u);
      d.z = (int)(((P2 >> sh) & 0x00FF00FFu) | 0x64006400u);
      d.w = (int)(((P3 >> sh) & 0x00FF00FFu) | 0x64006400u);
      *(int4*)(arow + qi * LSTRIDE) = d;   // rows 16B-aligned (144B pitch)
    }
  };

  // fv -> csum + fp16 pairs (transient hp) -> 2 m-groups x 2 p-shifts, b128
  auto bstage = [&]() {
    #pragma unroll
    for (int j = 1; j <= 16; ++j) csum_local += fv[j];  // pp=0 coverage: full W
    u32 hp[9];                         // transient: dead before next compute
    #pragma unroll
    for (int i = 0; i < 8; ++i) {
      u32 h0 = __builtin_bit_cast(unsigned short, (_Float16)fv[2 * i]);
      u32 h1 = __builtin_bit_cast(unsigned short, (_Float16)fv[2 * i + 1]);
      hp[i] = h0 | (h1 << 16);
    }
    hp[8] = (u32)__builtin_bit_cast(unsigned short, (_Float16)fv[16]);
    #pragma unroll
    for (int g = 0; g < 2; ++g) {
      const int mgrp = 2 * wave + g;
      int4 d1;                          // pp=1: even pairs, direct
      d1.x = (int)hp[4 * g + 0];
      d1.y = (int)hp[4 * g + 1];
      d1.z = (int)hp[4 * g + 2];
      d1.w = (int)hp[4 * g + 3];
      *(int4*)&Bs[(64 + lane) * LSTRIDE + mgrp * 8] = d1;
      int4 d0;                          // pp=0: odd pairs, alignbit extract
      d0.x = (int)((hp[4 * g + 0] >> 16) | (hp[4 * g + 1] << 16));
      d0.y = (int)((hp[4 * g + 1] >> 16) | (hp[4 * g + 2] << 16));
      d0.z = (int)((hp[4 * g + 2] >> 16) | (hp[4 * g + 3] << 16));
      d0.w = (int)((hp[4 * g + 3] >> 16) | (hp[4 * g + 4] << 16));
      *(int4*)&Bs[lane * LSTRIDE + mgrp * 8] = d0;
    }
  };

  auto compute_ks = [&](int ks) {
    const int koff = ks * 32 + quad * 8;
    half8 bf[4];
    #pragma unroll
    for (int nt = 0; nt < 4; ++nt)
      bf[nt] = *(const half8*)&Bs[(wn * 64 + nt * 16 + l16) * LSTRIDE + koff];
    #pragma unroll
    for (int mt = 0; mt < 4; ++mt) {
      half8 af = *(const half8*)&As[(wm * 64 + mt * 16 + l16) * LSTRIDE + koff];
      #pragma unroll
      for (int nt = 0; nt < 4; ++nt)
        acc[mt][nt] = __builtin_amdgcn_mfma_f32_16x16x32_f16(
            af, bf[nt], acc[mt][nt], 0, 0, 0);
    }
  };

  // ---- prologue: stage kc=0 (one-time exposed latency)
  xload(0); wload(0);
  astage(); bstage();
  __syncthreads();

  // ---- main loop: compute ks0 -> issue loads -> compute ks1 -> stage
  for (int kc = 0; kc < 8; ++kc) {
    compute_ks(0);
    if (kc < 7) {
      // keep VMEM below this point: load dests live only through ks1
      __builtin_amdgcn_sched_barrier(0x38F);   // all-but-VMEM may cross
      xload(kc + 1);
      wload(kc + 1);
    }
    compute_ks(1);
    __syncthreads();                   // all reads of tile kc done
    if (kc < 7) {
      astage();                        // consume arrived loads (pure VALU)
      bstage();
      __syncthreads();                 // tile kc+1 published
    }
  }

  // ---- csum reduction -> K1 * colsum(W)
  const float S = 2.0f / 255.0f;
  const float K1 = 1024.0f * S + 1.0f;
  part[t] = csum_local;
  __syncthreads();                     // also: all tile reads done, arena free
  if (t < 64)
    csumsh[t] = K1 * (part[t] + part[t + 64] + part[t + 128] + part[t + 192]);
  __syncthreads();

  float cs[4];
  #pragma unroll
  for (int nt = 0; nt < 4; ++nt) cs[nt] = csumsh[nt * 16 + l16];

  // ---- epilogue: two halves (8 subs each) staged in LDS (pitch 1040 f32),
  // then fully-coalesced stores: 64 lanes x 16B = 1KB contiguous per instr.
  float* ep = (float*)arena;           // 33280 B per half <= 36864
  #pragma unroll
  for (int h = 0; h < 2; ++h) {
    if (wm == h) {                     // waves wm==h own subs h*8..h*8+7
      #pragma unroll
      for (int mt = 0; mt < 4; ++mt)
        #pragma unroll
        for (int i = 0; i < 4; ++i) {
          const int mr = mt * 16 + quad * 4 + i;   // 0..63 local
          const int rowbase = (mr >> 3) * 1040 + wn * 512 + (mr & 7) * 64 + l16;
          #pragma unroll
          for (int nt = 0; nt < 4; ++nt)
            ep[rowbase + nt * 16] = __builtin_fmaf(S, acc[mt][nt][i], -cs[nt]);
        }
    }
    __syncthreads();
    const long outb =
        ((long)mtile * 16 + (long)h * 8) * 8192 + (long)y * 1024;
    #pragma unroll
    for (int k2 = 0; k2 < 8; ++k2) {
      const float4 v =
          *(const float4*)((const char*)ep + k2 * 4160 + wave * 1024 + lane * 16);
      *(float4*)&out[outb + (long)k2 * 8192 + wave * 256 + lane * 4] = v;
    }
    if (h == 0) __syncthreads();       // half-0 LDS reads done before re-stage
  }
}

extern "C" void kernel_launch(void* const* d_in, const int* in_sizes, int n_in,
                              void* d_out, int out_size, void* d_ws, size_t ws_size,
                              hipStream_t stream) {
  const int* x = (const int*)d_in[0];        // (256, 4096) byte values as int32
  const float* Wm = (const float*)d_in[1];   // (496, 64) fp32
  float* out = (float*)d_out;                // (256, 8, 128, 64) fp32
  byteformer_fused<<<dim3(128, 8), dim3(256), 0, stream>>>(x, Wm, out);
}

// Round 7
// 102.228 us; speedup vs baseline: 1.2189x; 1.0356x over previous
//
#include <hip/hip_runtime.h>

typedef unsigned short u16;
typedef unsigned int u32;
typedef _Float16 half8 __attribute__((ext_vector_type(8)));   // MFMA A/B frag
typedef __attribute__((ext_vector_type(4))) float floatx4;    // MFMA acc

#define LSTRIDE 72            // u16 per LDS row (64 data + 8 pad); bank-clean
#define TILE (128 * LSTRIDE)  // u16 per tile (18432 B)

// ---------------------------------------------------------------------------
// Single dispatch. TWO mtiles per block (B tile is mtile-invariant!):
//   grid 64x8, 2 blocks/CU, LDS = As0|As1|Bs = 55.3KB, launch_bounds(256,2)
//   -> 256 unified regs/wave: 128 AGPR (two acc sets) + ~80 VGPR, NO spill.
//   out[sub][p*8+q][o] = S*acc - K1*csum[o],  S = 2/255, K1 = 1024*S+1
// Per iter: 64 MFMA/wave between barriers (2x R6: amortizes barrier convoy),
// B staged once per two A tiles (halves W loads + B VALU per FLOP), bf frags
// read once and reused for both acc sets (-25% LDS reads).
// Loads for kc+1 issue at loop top: ~500cy of compute+stage cover them.
// Epilogue: LDS-staged 4 stages (8 subs each) -> coalesced 1KB/wave stores.
// ---------------------------------------------------------------------------
__global__ __launch_bounds__(256, 2) void byteformer_fused(
    const int* __restrict__ x, const float* __restrict__ Wm,
    float* __restrict__ out) {
  __shared__ __align__(16) u16 arena[3 * TILE];   // As0 | As1 | Bs = 55296 B
  __shared__ float part[256];
  __shared__ float csumsh[64];
  u16* As0 = arena;
  u16* As1 = arena + TILE;
  u16* Bs  = arena + 2 * TILE;

  const int t = threadIdx.x;
  const int bx = blockIdx.x;           // 0..63: mtiles 2bx, 2bx+1
  const int y = blockIdx.y;            // 0..7: p in {2y, 2y+1}

  const int wave = t >> 6, lane = t & 63;
  const int wm = wave >> 1, wn = wave & 1;
  const int quad = lane >> 4, l16 = lane & 15;

  // A staging: thread -> (sub, k-group, q-half)
  const int sA_sub = t >> 4;           // 0..15
  const int sA_kg  = (t >> 1) & 7;     // 0..7
  const int sA_qh  = t & 1;            // 0..1
  const long xrow0 = ((long)bx * 32 + sA_sub) * 512;
  const long xrow1 = xrow0 + 16 * 512;

  floatx4 acc0[4][4], acc1[4][4];
  #pragma unroll
  for (int mt = 0; mt < 4; ++mt)
    #pragma unroll
    for (int nt = 0; nt < 4; ++nt) {
      acc0[mt][nt] = floatx4{0.f, 0.f, 0.f, 0.f};
      acc1[mt][nt] = floatx4{0.f, 0.f, 0.f, 0.f};
    }

  float csum_local = 0.0f;

  // ---- register prefetch state (18 + 17 VGPRs; budget 128 -> no spill)
  int4 ca0, cb0, ca1, cb1; int cc0, cc1;   // x bytes, both mtiles
  float fv[17];                            // W rows (fp32)

  auto xload = [&](int kc) {
    const int base = kc * 64 + sA_kg * 8;
    ca0 = *(const int4*)&x[xrow0 + base];
    cb0 = *(const int4*)&x[xrow0 + base + 4];
    ca1 = *(const int4*)&x[xrow1 + base];
    cb1 = *(const int4*)&x[xrow1 + base + 4];
    const bool in = (base + 8 < 512);
    cc0 = in ? x[xrow0 + base + 8] : 0;
    cc1 = in ? x[xrow1 + base + 8] : 0;
  };

  auto wload = [&](int kc) {           // wave-uniform col, lane = o: coalesced
    const int cbase = kc * 64 + 16 * wave - 2 * y - 1;
    #pragma unroll
    for (int j = 0; j < 17; ++j) {
      const int c = cbase + j;
      fv[j] = (c >= 0 && c < 496) ? Wm[c * 64 + lane] : 0.0f;
    }
  };

  // bytes -> windows -> fp16(1024+v) via 0x6400|v; P-trick; b128 writes
  auto astage = [&](u16* As, const int4& a, const int4& b, int c8v) {
    const u32 c0 = (u32)a.x, c1 = (u32)a.y, c2 = (u32)a.z, c3 = (u32)a.w;
    const u32 c4 = (u32)b.x, c5 = (u32)b.y, c6 = (u32)b.z, c7 = (u32)b.w;
    const u32 c8 = (u32)c8v;
    const u32 P0 = ((c0 << 8) | c1) | (((c1 << 8) | c2) << 16);
    const u32 P1 = ((c2 << 8) | c3) | (((c3 << 8) | c4) << 16);
    const u32 P2 = ((c4 << 8) | c5) | (((c5 << 8) | c6) << 16);
    const u32 P3 = ((c6 << 8) | c7) | (((c7 << 8) | c8) << 16);
    u16* arow = &As[(sA_sub * 8 + sA_qh * 4) * LSTRIDE + sA_kg * 8];
    #pragma unroll
    for (int qi = 0; qi < 4; ++qi) {
      const int sh = 8 - (sA_qh * 4 + qi);
      int4 d;
      d.x = (int)(((P0 >> sh) & 0x00FF00FFu) | 0x64006400u);
      d.y = (int)(((P1 >> sh) & 0x00FF00FFu) | 0x64006400u);
      d.z = (int)(((P2 >> sh) & 0x00FF00FFu) | 0x64006400u);
      d.w = (int)(((P3 >> sh) & 0x00FF00FFu) | 0x64006400u);
      *(int4*)(arow + qi * LSTRIDE) = d;   // rows 16B-aligned (144B pitch)
    }
  };

  // fv -> csum + fp16 pairs (transient hp) -> 2 m-groups x 2 p-shifts, b128
  auto bstage = [&]() {
    #pragma unroll
    for (int j = 1; j <= 16; ++j) csum_local += fv[j];  // pp=0 coverage: full W
    u32 hp[9];                         // transient
    #pragma unroll
    for (int i = 0; i < 8; ++i) {
      u32 h0 = __builtin_bit_cast(unsigned short, (_Float16)fv[2 * i]);
      u32 h1 = __builtin_bit_cast(unsigned short, (_Float16)fv[2 * i + 1]);
      hp[i] = h0 | (h1 << 16);
    }
    hp[8] = (u32)__builtin_bit_cast(unsigned short, (_Float16)fv[16]);
    #pragma unroll
    for (int g = 0; g < 2; ++g) {
      const int mgrp = 2 * wave + g;
      int4 d1;                          // pp=1: even pairs, direct
      d1.x = (int)hp[4 * g + 0];
      d1.y = (int)hp[4 * g + 1];
      d1.z = (int)hp[4 * g + 2];
      d1.w = (int)hp[4 * g + 3];
      *(int4*)&Bs[(64 + lane) * LSTRIDE + mgrp * 8] = d1;
      int4 d0;                          // pp=0: odd pairs, alignbit extract
      d0.x = (int)((hp[4 * g + 0] >> 16) | (hp[4 * g + 1] << 16));
      d0.y = (int)((hp[4 * g + 1] >> 16) | (hp[4 * g + 2] << 16));
      d0.z = (int)((hp[4 * g + 2] >> 16) | (hp[4 * g + 3] << 16));
      d0.w = (int)((hp[4 * g + 3] >> 16) | (hp[4 * g + 4] << 16));
      *(int4*)&Bs[lane * LSTRIDE + mgrp * 8] = d0;
    }
  };

  auto compute_ks = [&](int ks) {
    const int koff = ks * 32 + quad * 8;
    half8 bf[4];
    #pragma unroll
    for (int nt = 0; nt < 4; ++nt)
      bf[nt] = *(const half8*)&Bs[(wn * 64 + nt * 16 + l16) * LSTRIDE + koff];
    #pragma unroll
    for (int mt = 0; mt < 4; ++mt) {
      const int ar = (wm * 64 + mt * 16 + l16) * LSTRIDE + koff;
      half8 af0 = *(const half8*)&As0[ar];
      half8 af1 = *(const half8*)&As1[ar];
      #pragma unroll
      for (int nt = 0; nt < 4; ++nt) {
        acc0[mt][nt] = __builtin_amdgcn_mfma_f32_16x16x32_f16(
            af0, bf[nt], acc0[mt][nt], 0, 0, 0);
        acc1[mt][nt] = __builtin_amdgcn_mfma_f32_16x16x32_f16(
            af1, bf[nt], acc1[mt][nt], 0, 0, 0);
      }
    }
  };

  // ---- prologue: stage kc=0 (one-time exposed latency)
  xload(0); wload(0);
  astage(As0, ca0, cb0, cc0);
  astage(As1, ca1, cb1, cc1);
  bstage();
  __syncthreads();

  // ---- main loop: 64 MFMA/wave between barrier pairs
  for (int kc = 0; kc < 8; ++kc) {
    if (kc < 7) { xload(kc + 1); wload(kc + 1); }  // covered by ~500cy below
    compute_ks(0);
    compute_ks(1);
    __syncthreads();                   // all reads of tile kc done
    if (kc < 7) {
      astage(As0, ca0, cb0, cc0);      // consume arrived loads (pure VALU)
      astage(As1, ca1, cb1, cc1);
      bstage();
      __syncthreads();                 // tiles kc+1 published
    }
  }

  // ---- csum reduction -> K1 * colsum(W)
  const float S = 2.0f / 255.0f;
  const float K1 = 1024.0f * S + 1.0f;
  part[t] = csum_local;
  __syncthreads();                     // also: all tile reads done, arena free
  if (t < 64)
    csumsh[t] = K1 * (part[t] + part[t + 64] + part[t + 128] + part[t + 192]);
  __syncthreads();

  float cs[4];
  #pragma unroll
  for (int nt = 0; nt < 4; ++nt) cs[nt] = csumsh[nt * 16 + l16];

  // ---- epilogue: 4 stages (mtile mi, sub-half hh), 8 subs each staged in
  // LDS (pitch 1040 f32) -> fully-coalesced 1KB/wave-instr stores.
  float* ep = (float*)arena;           // 33280 B per stage <= 55296
  auto epi_fill = [&](const floatx4 (&A)[4][4]) {
    #pragma unroll
    for (int mt = 0; mt < 4; ++mt)
      #pragma unroll
      for (int i = 0; i < 4; ++i) {
        const int mr = mt * 16 + quad * 4 + i;   // 0..63 local
        const int rowbase = (mr >> 3) * 1040 + wn * 512 + (mr & 7) * 64 + l16;
        #pragma unroll
        for (int nt = 0; nt < 4; ++nt)
          ep[rowbase + nt * 16] = __builtin_fmaf(S, A[mt][nt][i], -cs[nt]);
      }
  };

  #pragma unroll
  for (int h = 0; h < 4; ++h) {
    const int mi = h >> 1, hh = h & 1;
    if (wm == hh) {                    // waves wm==hh own subs hh*8..hh*8+7
      if (mi == 0) epi_fill(acc0); else epi_fill(acc1);
    }
    __syncthreads();
    const long outb =
        ((long)(2 * bx + mi) * 16 + (long)hh * 8) * 8192 + (long)y * 1024;
    #pragma unroll
    for (int k2 = 0; k2 < 8; ++k2) {
      const float4 v =
          *(const float4*)((const char*)ep + k2 * 4160 + wave * 1024 + lane * 16);
      *(float4*)&out[outb + (long)k2 * 8192 + wave * 256 + lane * 4] = v;
    }
    if (h < 3) __syncthreads();        // stage's LDS reads done before re-fill
  }
}

extern "C" void kernel_launch(void* const* d_in, const int* in_sizes, int n_in,
                              void* d_out, int out_size, void* d_ws, size_t ws_size,
                              hipStream_t stream) {
  const int* x = (const int*)d_in[0];        // (256, 4096) byte values as int32
  const float* Wm = (const float*)d_in[1];   // (496, 64) fp32
  float* out = (float*)d_out;                // (256, 8, 128, 64) fp32
  byteformer_fused<<<dim3(64, 8), dim3(256), 0, stream>>>(x, Wm, out);
}